// Round 4
// baseline (148.545 us; speedup 1.0000x reference)
//
#include <hip/hip_runtime.h>

// N=512, D=512 pairwise scorer, all f32.
// left = E@W1[:D]; right = E@W1[D:]+b1; h = left[i]+right[j]; LN(D); GELU; @W2+b2; sigmoid.
// LN stats decompose: var = var_l[i]+var_r[j]+2*cov(i,j), cov = (1/D) lc@rc^T (centered).
// Never materialize [N,N,D]. Upper-triangle 16x16 pair tiles, mirrored store.

#define N_ 512
#define D_ 512
#define EP 516   // LDS row stride (mod 32 == 4): row-broadcast reads conflict-free

// ---------------- K1: left/right GEMMs ----------------
// 512 blocks = rowgrp(16: 32 rows) x ccgrp(32: 32 cols of combined 1024).
// 256 threads: tr = t>>3 (row 0..31), tc = t&7 (col quad). 4 outputs/thread.
// E row-block staged once in LDS (64.5KB); W1 read as one 128B segment per
// (wave,k) -> total W1 L2 traffic ~33MB. 2 blocks/CU, 8 waves/CU.
__global__ __launch_bounds__(256) void k_gemm(const float* __restrict__ E,
                                              const float* __restrict__ W1,
                                              const float* __restrict__ b1,
                                              float* __restrict__ W /* [1024][512] */) {
    __shared__ float e[32][EP];
    const int t = threadIdx.x;
    const int ccgrp = blockIdx.x & 31;
    const int r0 = (blockIdx.x >> 5) * 32;
    const int cc0 = ccgrp * 32;
    const int half = cc0 >> 9;
    const int c = (cc0 & 511) + (t & 7) * 4;
    const int tr = t >> 3;

    // stage E rows r0..r0+31 (coalesced float4 loads, b128 LDS writes)
    for (int x = t; x < 32 * 128; x += 256) {
        int r = x >> 7, c4 = (x & 127) << 2;
        *(float4*)&e[r][c4] = *(const float4*)&E[(r0 + r) * D_ + c4];
    }
    __syncthreads();

    const float* __restrict__ wp = W1 + (half << 18) + c;
    float4 acc = {0.f, 0.f, 0.f, 0.f};
#pragma unroll 8
    for (int k = 0; k < D_; ++k) {
        float eb = e[tr][k];                      // 8-lane broadcast, conflict-free
        float4 w4 = *(const float4*)(wp + (k << 9));
        acc.x = fmaf(eb, w4.x, acc.x);
        acc.y = fmaf(eb, w4.y, acc.y);
        acc.z = fmaf(eb, w4.z, acc.z);
        acc.w = fmaf(eb, w4.w, acc.w);
    }
    if (half) {
        float4 bb = *(const float4*)(b1 + c);
        acc.x += bb.x; acc.y += bb.y; acc.z += bb.z; acc.w += bb.w;
    }
    *(float4*)(W + ((half << 9) + r0 + tr) * D_ + ((cc0 & 511) + (t & 7) * 4)) = acc;
}

// ---------------- K2: center rows, per-row variance ----------------
__device__ __forceinline__ float block_sum(float v, float* sred, int t) {
#pragma unroll
    for (int off = 32; off > 0; off >>= 1) v += __shfl_xor(v, off, 64);
    int wave = t >> 6;
    if ((t & 63) == 0) sred[wave] = v;
    __syncthreads();
    float s = sred[0] + sred[1] + sred[2] + sred[3];
    __syncthreads();
    return s;
}

__global__ __launch_bounds__(256) void k_center(float* __restrict__ W,
                                                float* __restrict__ var) {
    __shared__ float sred[4];
    const int r = blockIdx.x, t = threadIdx.x;
    float* p = W + r * D_;
    float v0 = p[t], v1 = p[t + 256];
    float s = block_sum(v0 + v1, sred, t);
    float mean = s * (1.f / D_);
    float c0 = v0 - mean, c1 = v1 - mean;
    float ss = block_sum(c0 * c0 + c1 * c1, sred, t);
    p[t] = c0;
    p[t + 256] = c1;
    if (t == 0) var[r] = ss * (1.f / D_);
}

// ---------------- K3: fused cov -> rstd -> gelu-dot -> sigmoid ----------------
// 528 blocks = upper-triangle 16x16 pair tiles. 512 threads (8 waves):
// p = t&255 is the pair, h = t>>8 is the k-half. Full 512-k tile staged ONCE
// in LDS; pass A (cov) and pass B (gelu-dot) each do 256 k per thread; partials
// combined through a tiny LDS array. 66KB LDS -> 2 blocks/CU = 16 waves/CU.
__device__ __forceinline__ void gelu_acc(float l, float r, float g, float be,
                                         float w, float rstd, float& acc) {
    // gelu_tanh(x) = x * sigmoid(1.5957691*(x + 0.044715 x^3))
    // q = log2(exp(-2y)) = x*(A*x^2 + B), B = -2*log2e*0.79788456, A = B*0.044715
    float s = l + r;
    float x = fmaf(s * rstd, g, be);
    float x2 = x * x;
    float q = x * fmaf(-0.10294340f, x2, -2.30220935f);
    float eq = __builtin_amdgcn_exp2f(q);
    float ge = x * __builtin_amdgcn_rcpf(1.f + eq);
    acc = fmaf(ge, w, acc);
}

__global__ __launch_bounds__(512) void k_pair(const float* __restrict__ W,
                                              const float* __restrict__ var,
                                              const float* __restrict__ gf,
                                              const float* __restrict__ bef,
                                              const float* __restrict__ wf,
                                              const float* __restrict__ b2f,
                                              float* __restrict__ out) {
    __shared__ float ls[16][EP];
    __shared__ float rs[16][EP];
    __shared__ float covp[2][256];
    __shared__ float accp[2][256];

    // decode upper-triangle tile index b -> (I, J), I<=J, 32 tile-rows
    const int b = blockIdx.x;
    int I = (int)((65.0f - sqrtf(4225.0f - 8.0f * (float)b)) * 0.5f);
    if (I < 0) I = 0;
    if (I > 31) I = 31;
#define S_(i) (32 * (i) - ((i) * ((i)-1)) / 2)
    while (S_(I) > b) --I;
    while (S_(I + 1) <= b) ++I;
    const int J = I + (b - S_(I));
#undef S_

    const int t = threadIdx.x;
    const int p = t & 255, h = t >> 8;
    const int ti = p & 15, tj = p >> 4;
    const int gi = I * 16 + ti, gj = J * 16 + tj;
    const int Ibase = I * 16, Jbase = N_ + J * 16;
    const int kb = h << 8;

    // stage full 512-k tiles once (coalesced)
    for (int x = t; x < 16 * 128; x += 512) {
        int r = x >> 7, c4 = (x & 127) << 2;
        *(float4*)&ls[r][c4] = *(const float4*)&W[(Ibase + r) * D_ + c4];
        *(float4*)&rs[r][c4] = *(const float4*)&W[(Jbase + r) * D_ + c4];
    }
    __syncthreads();

    // ---- pass A: cov partial over this thread's k-half ----
    float cov = 0.f;
#pragma unroll 8
    for (int k = 0; k < 256; k += 4) {
        float4 lv = *(float4*)&ls[ti][kb + k];
        float4 rv = *(float4*)&rs[tj][kb + k];
        cov += lv.x * rv.x + lv.y * rv.y + lv.z * rv.z + lv.w * rv.w;
    }
    covp[h][p] = cov;
    __syncthreads();
    float varh = var[gi] + var[N_ + gj] +
                 2.f * (covp[0][p] + covp[1][p]) * (1.f / D_);
    float rstd = rsqrtf(varh + 1e-5f);

    // ---- pass B: gelu dot partial ----
    float acc = 0.f;
#pragma unroll 4
    for (int k = 0; k < 256; k += 4) {
        float4 lv = *(float4*)&ls[ti][kb + k];
        float4 rv = *(float4*)&rs[tj][kb + k];
        float4 g4 = *(const float4*)&gf[kb + k];
        float4 be4 = *(const float4*)&bef[kb + k];
        float4 w4 = *(const float4*)&wf[kb + k];
        gelu_acc(lv.x, rv.x, g4.x, be4.x, w4.x, rstd, acc);
        gelu_acc(lv.y, rv.y, g4.y, be4.y, w4.y, rstd, acc);
        gelu_acc(lv.z, rv.z, g4.z, be4.z, w4.z, rstd, acc);
        gelu_acc(lv.w, rv.w, g4.w, be4.w, w4.w, rstd, acc);
    }
    accp[h][p] = acc;
    __syncthreads();

    if (h == 0 && gi <= gj) {
        float z = accp[0][p] + accp[1][p] + b2f[0];
        float sg = __builtin_amdgcn_rcpf(1.f + __builtin_amdgcn_exp2f(-1.44269504f * z));
        out[gi * N_ + gj] = sg;
        out[gj * N_ + gi] = sg;
    }
}

extern "C" void kernel_launch(void* const* d_in, const int* in_sizes, int n_in,
                              void* d_out, int out_size, void* d_ws, size_t ws_size,
                              hipStream_t stream) {
    const float* E     = (const float*)d_in[0];
    const float* W1    = (const float*)d_in[1];
    const float* b1    = (const float*)d_in[2];
    const float* gamma = (const float*)d_in[3];
    const float* beta  = (const float*)d_in[4];
    const float* w2    = (const float*)d_in[5];
    const float* b2    = (const float*)d_in[6];
    float* out = (float*)d_out;

    float* F    = (float*)d_ws;
    float* lcrc = F;                  // [1024][512]: rows 0..511 lc, 512..1023 rc(+b1)
    float* var  = F + 1024 * 512;     // [1024]

    k_gemm<<<512, 256, 0, stream>>>(E, W1, b1, lcrc);
    k_center<<<1024, 256, 0, stream>>>(lcrc, var);
    k_pair<<<528, 512, 0, stream>>>(lcrc, var, gamma, beta, w2, b2, out);
}

// Round 5
// 141.773 us; speedup vs baseline: 1.0478x; 1.0478x over previous
//
#include <hip/hip_runtime.h>

// N=512, D=512 pairwise scorer, all f32.
// left = E@W1[:D]; right = E@W1[D:]+b1; h = left[i]+right[j]; LN(D); GELU; @W2+b2; sigmoid.
// LN stats decompose: var = var_l[i]+var_r[j]+2*cov(i,j), cov = (1/D) lc@rc^T (centered).
// Never materialize [N,N,D]. Upper-triangle 16x16 pair tiles, mirrored store.

#define N_ 512
#define D_ 512
#define EP 516   // LDS row stride (mod 32 == 4): broadcast row-reads <=2-way (free)

// ---------------- K1: left/right GEMMs ----------------
// 512 blocks = 32 rowgrps (16 rows) x 16 ccgrps (64 combined cols of 1024).
// 256 thr: tr = t>>4 (row), t&15 -> col quad. E block staged in LDS (33KB),
// read as b128 (4 k per ds_read). W1: one 256B wave-segment per k, L1-reused
// across the 16 rows. 4 independent FMA chains/thread.
__global__ __launch_bounds__(256) void k_gemm(const float* __restrict__ E,
                                              const float* __restrict__ W1,
                                              const float* __restrict__ b1,
                                              float* __restrict__ W /* [1024][512] */) {
    __shared__ float e[16][EP];
    const int t = threadIdx.x;
    const int ccgrp = blockIdx.x & 15;
    const int r0 = (blockIdx.x >> 4) * 16;
    const int cc0 = ccgrp * 64;
    const int half = cc0 >> 9;
    const int c = (cc0 & 511) + (t & 15) * 4;
    const int tr = t >> 4;

    for (int x = t; x < 16 * 128; x += 256) {
        int r = x >> 7, c4 = (x & 127) << 2;
        *(float4*)&e[r][c4] = *(const float4*)&E[(r0 + r) * D_ + c4];
    }
    __syncthreads();

    const float* __restrict__ wp = W1 + (half << 18) + c;
    float4 acc = {0.f, 0.f, 0.f, 0.f};
#pragma unroll 4
    for (int k = 0; k < D_; k += 4) {
        float4 e4 = *(float4*)&e[tr][k];
        float4 wa = *(const float4*)(wp + ((k + 0) << 9));
        float4 wb = *(const float4*)(wp + ((k + 1) << 9));
        float4 wc = *(const float4*)(wp + ((k + 2) << 9));
        float4 wd = *(const float4*)(wp + ((k + 3) << 9));
        acc.x = fmaf(e4.x, wa.x, acc.x); acc.y = fmaf(e4.x, wa.y, acc.y);
        acc.z = fmaf(e4.x, wa.z, acc.z); acc.w = fmaf(e4.x, wa.w, acc.w);
        acc.x = fmaf(e4.y, wb.x, acc.x); acc.y = fmaf(e4.y, wb.y, acc.y);
        acc.z = fmaf(e4.y, wb.z, acc.z); acc.w = fmaf(e4.y, wb.w, acc.w);
        acc.x = fmaf(e4.z, wc.x, acc.x); acc.y = fmaf(e4.z, wc.y, acc.y);
        acc.z = fmaf(e4.z, wc.z, acc.z); acc.w = fmaf(e4.z, wc.w, acc.w);
        acc.x = fmaf(e4.w, wd.x, acc.x); acc.y = fmaf(e4.w, wd.y, acc.y);
        acc.z = fmaf(e4.w, wd.z, acc.z); acc.w = fmaf(e4.w, wd.w, acc.w);
    }
    if (half) {
        float4 bb = *(const float4*)(b1 + c);
        acc.x += bb.x; acc.y += bb.y; acc.z += bb.z; acc.w += bb.w;
    }
    *(float4*)(W + ((half << 9) + r0 + tr) * D_ + c) = acc;
}

// ---------------- K2: center rows, per-row variance ----------------
__device__ __forceinline__ float block_sum(float v, float* sred, int t) {
#pragma unroll
    for (int off = 32; off > 0; off >>= 1) v += __shfl_xor(v, off, 64);
    int wave = t >> 6;
    if ((t & 63) == 0) sred[wave] = v;
    __syncthreads();
    float s = sred[0] + sred[1] + sred[2] + sred[3];
    __syncthreads();
    return s;
}

__global__ __launch_bounds__(256) void k_center(float* __restrict__ W,
                                                float* __restrict__ var) {
    __shared__ float sred[4];
    const int r = blockIdx.x, t = threadIdx.x;
    float* p = W + r * D_;
    float v0 = p[t], v1 = p[t + 256];
    float s = block_sum(v0 + v1, sred, t);
    float mean = s * (1.f / D_);
    float c0 = v0 - mean, c1 = v1 - mean;
    float ss = block_sum(c0 * c0 + c1 * c1, sred, t);
    p[t] = c0;
    p[t + 256] = c1;
    if (t == 0) var[r] = ss * (1.f / D_);
}

// ---------------- K3: fused cov -> rstd -> gelu-dot -> sigmoid ----------------
// 528 blocks = upper-triangle 16x16 pair tiles. 256 threads:
// p = t&63 -> 8x8 grid of 2x2 pair quads; h = t>>6 -> k-quarter (128 k).
// Each thread owns 4 pairs: 4 b128 LDS reads feed 16 gelu elements.
// Full 512-k tile staged once (74KB LDS -> 2 blocks/CU).
__device__ __forceinline__ void gelu_acc(float l, float r, float g, float be,
                                         float w, float rstd, float& acc) {
    // gelu_tanh(x) = x * sigmoid(1.5957691*(x + 0.044715 x^3))
    // q = log2(exp(-2y)) = x*(A*x^2 + B), B = -2*log2e*0.79788456, A = B*0.044715
    float s = l + r;
    float x = fmaf(s * rstd, g, be);
    float x2 = x * x;
    float q = x * fmaf(-0.10294340f, x2, -2.30220935f);
    float eq = __builtin_amdgcn_exp2f(q);
    float ge = x * __builtin_amdgcn_rcpf(1.f + eq);
    acc = fmaf(ge, w, acc);
}

__global__ __launch_bounds__(256) void k_pair(const float* __restrict__ W,
                                              const float* __restrict__ var,
                                              const float* __restrict__ gf,
                                              const float* __restrict__ bef,
                                              const float* __restrict__ wf,
                                              const float* __restrict__ b2f,
                                              float* __restrict__ out) {
    __shared__ float ls[16][EP];
    __shared__ float rs[16][EP];
    __shared__ float4 covp[4][64];
    __shared__ float4 accp[4][64];

    // decode upper-triangle tile index b -> (I, J), I<=J, 32 tile-rows
    const int b = blockIdx.x;
    int I = (int)((65.0f - sqrtf(4225.0f - 8.0f * (float)b)) * 0.5f);
    if (I < 0) I = 0;
    if (I > 31) I = 31;
#define S_(i) (32 * (i) - ((i) * ((i)-1)) / 2)
    while (S_(I) > b) --I;
    while (S_(I + 1) <= b) ++I;
    const int J = I + (b - S_(I));
#undef S_

    const int t = threadIdx.x;
    const int p = t & 63, h = t >> 6;
    const int i2 = (p & 7) * 2, j2 = (p >> 3) * 2;
    const int kb = h * 128;
    const int Ibase = I * 16, Jbase = N_ + J * 16;

    // stage full 512-k tiles once (coalesced b128)
    for (int x = t; x < 16 * 128; x += 256) {
        int r = x >> 7, c4 = (x & 127) << 2;
        *(float4*)&ls[r][c4] = *(const float4*)&W[(Ibase + r) * D_ + c4];
        *(float4*)&rs[r][c4] = *(const float4*)&W[(Jbase + r) * D_ + c4];
    }
    __syncthreads();

    // ---- pass A: 4 cov partials over this thread's k-quarter ----
    float c00 = 0.f, c01 = 0.f, c10 = 0.f, c11 = 0.f;
#pragma unroll 8
    for (int k = 0; k < 128; k += 4) {
        float4 l0 = *(float4*)&ls[i2][kb + k];
        float4 l1 = *(float4*)&ls[i2 + 1][kb + k];
        float4 q0 = *(float4*)&rs[j2][kb + k];
        float4 q1 = *(float4*)&rs[j2 + 1][kb + k];
        c00 += l0.x * q0.x + l0.y * q0.y + l0.z * q0.z + l0.w * q0.w;
        c01 += l0.x * q1.x + l0.y * q1.y + l0.z * q1.z + l0.w * q1.w;
        c10 += l1.x * q0.x + l1.y * q0.y + l1.z * q0.z + l1.w * q0.w;
        c11 += l1.x * q1.x + l1.y * q1.y + l1.z * q1.z + l1.w * q1.w;
    }
    covp[h][p] = make_float4(c00, c01, c10, c11);
    __syncthreads();

    const int gi0 = I * 16 + i2, gj0 = J * 16 + j2;
    float4 ca = covp[0][p], cb = covp[1][p], cc = covp[2][p], cd = covp[3][p];
    float sx = ca.x + cb.x + cc.x + cd.x;
    float sy = ca.y + cb.y + cc.y + cd.y;
    float sz = ca.z + cb.z + cc.z + cd.z;
    float sw = ca.w + cb.w + cc.w + cd.w;
    float vi0 = var[gi0], vi1 = var[gi0 + 1];
    float vj0 = var[N_ + gj0], vj1 = var[N_ + gj0 + 1];
    float r00 = rsqrtf(vi0 + vj0 + sx * (2.f / D_) + 1e-5f);
    float r01 = rsqrtf(vi0 + vj1 + sy * (2.f / D_) + 1e-5f);
    float r10 = rsqrtf(vi1 + vj0 + sz * (2.f / D_) + 1e-5f);
    float r11 = rsqrtf(vi1 + vj1 + sw * (2.f / D_) + 1e-5f);

    // ---- pass B: gelu-dot partials for 4 pairs ----
    float a00 = 0.f, a01 = 0.f, a10 = 0.f, a11 = 0.f;
#pragma unroll 2
    for (int k = 0; k < 128; k += 4) {
        float4 l0 = *(float4*)&ls[i2][kb + k];
        float4 l1 = *(float4*)&ls[i2 + 1][kb + k];
        float4 q0 = *(float4*)&rs[j2][kb + k];
        float4 q1 = *(float4*)&rs[j2 + 1][kb + k];
        float4 g4 = *(const float4*)&gf[kb + k];
        float4 be4 = *(const float4*)&bef[kb + k];
        float4 w4 = *(const float4*)&wf[kb + k];
        gelu_acc(l0.x, q0.x, g4.x, be4.x, w4.x, r00, a00);
        gelu_acc(l0.x, q1.x, g4.x, be4.x, w4.x, r01, a01);
        gelu_acc(l1.x, q0.x, g4.x, be4.x, w4.x, r10, a10);
        gelu_acc(l1.x, q1.x, g4.x, be4.x, w4.x, r11, a11);
        gelu_acc(l0.y, q0.y, g4.y, be4.y, w4.y, r00, a00);
        gelu_acc(l0.y, q1.y, g4.y, be4.y, w4.y, r01, a01);
        gelu_acc(l1.y, q0.y, g4.y, be4.y, w4.y, r10, a10);
        gelu_acc(l1.y, q1.y, g4.y, be4.y, w4.y, r11, a11);
        gelu_acc(l0.z, q0.z, g4.z, be4.z, w4.z, r00, a00);
        gelu_acc(l0.z, q1.z, g4.z, be4.z, w4.z, r01, a01);
        gelu_acc(l1.z, q0.z, g4.z, be4.z, w4.z, r10, a10);
        gelu_acc(l1.z, q1.z, g4.z, be4.z, w4.z, r11, a11);
        gelu_acc(l0.w, q0.w, g4.w, be4.w, w4.w, r00, a00);
        gelu_acc(l0.w, q1.w, g4.w, be4.w, w4.w, r01, a01);
        gelu_acc(l1.w, q0.w, g4.w, be4.w, w4.w, r10, a10);
        gelu_acc(l1.w, q1.w, g4.w, be4.w, w4.w, r11, a11);
    }
    accp[h][p] = make_float4(a00, a01, a10, a11);
    __syncthreads();

    if (h == 0) {
        float4 aa = accp[0][p], ab = accp[1][p], ac = accp[2][p], ad = accp[3][p];
        float z00 = aa.x + ab.x + ac.x + ad.x + b2f[0];
        float z01 = aa.y + ab.y + ac.y + ad.y + b2f[0];
        float z10 = aa.z + ab.z + ac.z + ad.z + b2f[0];
        float z11 = aa.w + ab.w + ac.w + ad.w + b2f[0];
        float s00 = __builtin_amdgcn_rcpf(1.f + __builtin_amdgcn_exp2f(-1.44269504f * z00));
        float s01 = __builtin_amdgcn_rcpf(1.f + __builtin_amdgcn_exp2f(-1.44269504f * z01));
        float s10 = __builtin_amdgcn_rcpf(1.f + __builtin_amdgcn_exp2f(-1.44269504f * z10));
        float s11 = __builtin_amdgcn_rcpf(1.f + __builtin_amdgcn_exp2f(-1.44269504f * z11));
        if (gi0 <= gj0)         { out[gi0 * N_ + gj0] = s00;           out[gj0 * N_ + gi0] = s00; }
        if (gi0 <= gj0 + 1)     { out[gi0 * N_ + gj0 + 1] = s01;       out[(gj0 + 1) * N_ + gi0] = s01; }
        if (gi0 + 1 <= gj0)     { out[(gi0 + 1) * N_ + gj0] = s10;     out[gj0 * N_ + gi0 + 1] = s10; }
        if (gi0 + 1 <= gj0 + 1) { out[(gi0 + 1) * N_ + gj0 + 1] = s11; out[(gj0 + 1) * N_ + gi0 + 1] = s11; }
    }
}

extern "C" void kernel_launch(void* const* d_in, const int* in_sizes, int n_in,
                              void* d_out, int out_size, void* d_ws, size_t ws_size,
                              hipStream_t stream) {
    const float* E     = (const float*)d_in[0];
    const float* W1    = (const float*)d_in[1];
    const float* b1    = (const float*)d_in[2];
    const float* gamma = (const float*)d_in[3];
    const float* beta  = (const float*)d_in[4];
    const float* w2    = (const float*)d_in[5];
    const float* b2    = (const float*)d_in[6];
    float* out = (float*)d_out;

    float* F    = (float*)d_ws;
    float* lcrc = F;                  // [1024][512]: rows 0..511 lc, 512..1023 rc(+b1)
    float* var  = F + 1024 * 512;     // [1024]

    k_gemm<<<512, 256, 0, stream>>>(E, W1, b1, lcrc);
    k_center<<<1024, 256, 0, stream>>>(lcrc, var);
    k_pair<<<528, 256, 0, stream>>>(lcrc, var, gamma, beta, w2, b2, out);
}

// Round 6
// 132.023 us; speedup vs baseline: 1.1251x; 1.0738x over previous
//
#include <hip/hip_runtime.h>

// N=512, D=512 pairwise scorer, all f32.
// left = E@W1[:D]; right = E@W1[D:]+b1; h = left[i]+right[j]; LN(D); GELU; @W2+b2; sigmoid.
// LN stats decompose: var = var_l[i]+var_r[j]+2*cov(i,j), cov = (1/D) lc@rc^T (centered).
// Never materialize [N,N,D]. Upper-triangle 16x16 pair tiles, mirrored store.

#define N_ 512
#define D_ 512

// ---------------- K1: left/right GEMMs ----------------
// 256 blocks = 32 rowgrps (16 rows) x 8 ccgrps (128 combined cols of 1024).
// 256 thr: t&31 -> col quad (128 cols), t>>5 -> row pair. 2 rows x 4 cols each:
// 32 FMA per (2 ds_read_b128 + 4 global dwordx4). W1 L2 traffic 64MB (~2us).
__global__ __launch_bounds__(256) void k_gemm(const float* __restrict__ E,
                                              const float* __restrict__ W1,
                                              const float* __restrict__ b1,
                                              float* __restrict__ W /* [1024][512] */) {
    __shared__ float e[16][516];  // 516 mod 32 = 4: 2-row stride -> 8 -> free 2-way
    const int t = threadIdx.x;
    const int cc = (blockIdx.x & 7) * 128;     // combined col base (0..896)
    const int r0 = (blockIdx.x >> 3) * 16;
    const int half = cc >> 9;
    const int c = (cc & 511) + (t & 31) * 4;
    const int rp = (t >> 5) * 2;

    for (int x = t; x < 16 * 128; x += 256) {
        int r = x >> 7, c4 = (x & 127) << 2;
        *(float4*)&e[r][c4] = *(const float4*)&E[(r0 + r) * D_ + c4];
    }
    __syncthreads();

    const float* __restrict__ wp = W1 + (half << 18) + c;
    float4 a0 = {0.f, 0.f, 0.f, 0.f}, a1 = {0.f, 0.f, 0.f, 0.f};
#pragma unroll 4
    for (int k = 0; k < D_; k += 4) {
        float4 e0 = *(float4*)&e[rp][k];
        float4 e1 = *(float4*)&e[rp + 1][k];
        float4 wa = *(const float4*)(wp + ((k + 0) << 9));
        float4 wb = *(const float4*)(wp + ((k + 1) << 9));
        float4 wc = *(const float4*)(wp + ((k + 2) << 9));
        float4 wd = *(const float4*)(wp + ((k + 3) << 9));
        a0.x = fmaf(e0.x, wa.x, a0.x); a0.y = fmaf(e0.x, wa.y, a0.y);
        a0.z = fmaf(e0.x, wa.z, a0.z); a0.w = fmaf(e0.x, wa.w, a0.w);
        a1.x = fmaf(e1.x, wa.x, a1.x); a1.y = fmaf(e1.x, wa.y, a1.y);
        a1.z = fmaf(e1.x, wa.z, a1.z); a1.w = fmaf(e1.x, wa.w, a1.w);
        a0.x = fmaf(e0.y, wb.x, a0.x); a0.y = fmaf(e0.y, wb.y, a0.y);
        a0.z = fmaf(e0.y, wb.z, a0.z); a0.w = fmaf(e0.y, wb.w, a0.w);
        a1.x = fmaf(e1.y, wb.x, a1.x); a1.y = fmaf(e1.y, wb.y, a1.y);
        a1.z = fmaf(e1.y, wb.z, a1.z); a1.w = fmaf(e1.y, wb.w, a1.w);
        a0.x = fmaf(e0.z, wc.x, a0.x); a0.y = fmaf(e0.z, wc.y, a0.y);
        a0.z = fmaf(e0.z, wc.z, a0.z); a0.w = fmaf(e0.z, wc.w, a0.w);
        a1.x = fmaf(e1.z, wc.x, a1.x); a1.y = fmaf(e1.z, wc.y, a1.y);
        a1.z = fmaf(e1.z, wc.z, a1.z); a1.w = fmaf(e1.z, wc.w, a1.w);
        a0.x = fmaf(e0.w, wd.x, a0.x); a0.y = fmaf(e0.w, wd.y, a0.y);
        a0.z = fmaf(e0.w, wd.z, a0.z); a0.w = fmaf(e0.w, wd.w, a0.w);
        a1.x = fmaf(e1.w, wd.x, a1.x); a1.y = fmaf(e1.w, wd.y, a1.y);
        a1.z = fmaf(e1.w, wd.z, a1.z); a1.w = fmaf(e1.w, wd.w, a1.w);
    }
    if (half) {
        float4 bb = *(const float4*)(b1 + c);
        a0.x += bb.x; a0.y += bb.y; a0.z += bb.z; a0.w += bb.w;
        a1.x += bb.x; a1.y += bb.y; a1.z += bb.z; a1.w += bb.w;
    }
    *(float4*)(W + ((half << 9) + r0 + rp) * D_ + c) = a0;
    *(float4*)(W + ((half << 9) + r0 + rp + 1) * D_ + c) = a1;
}

// ---------------- K2: center rows, per-row variance ----------------
__device__ __forceinline__ float block_sum(float v, float* sred, int t) {
#pragma unroll
    for (int off = 32; off > 0; off >>= 1) v += __shfl_xor(v, off, 64);
    int wave = t >> 6;
    if ((t & 63) == 0) sred[wave] = v;
    __syncthreads();
    float s = sred[0] + sred[1] + sred[2] + sred[3];
    __syncthreads();
    return s;
}

__global__ __launch_bounds__(256) void k_center(float* __restrict__ W,
                                                float* __restrict__ var) {
    __shared__ float sred[4];
    const int r = blockIdx.x, t = threadIdx.x;
    float* p = W + r * D_;
    float v0 = p[t], v1 = p[t + 256];
    float s = block_sum(v0 + v1, sred, t);
    float mean = s * (1.f / D_);
    float c0 = v0 - mean, c1 = v1 - mean;
    float ss = block_sum(c0 * c0 + c1 * c1, sred, t);
    p[t] = c0;
    p[t + 256] = c1;
    if (t == 0) var[r] = ss * (1.f / D_);
}

// ---------------- K3: fused cov -> rstd -> gelu-dot -> sigmoid ----------------
// 528 blocks = upper-triangle 16x16 pair tiles. 256 thr = 16 pair-threads (pt,
// each a 4x4 pair block: 16 indep chains) x 16 k-slices (ks owns float4-quads
// ks, ks+16, ... -> wave addresses spread all 8 bank-quads). k chunked at 256
// (33KB tile + 16KB reduce + 1KB rstd ~ 50KB -> 3 blocks/CU).
__device__ __forceinline__ void gelu_acc(float l, float r, float g, float be,
                                         float w, float rstd, float& acc) {
    // gelu_tanh(x) = x * sigmoid(1.5957691*(x + 0.044715 x^3))
    // q = log2(exp(-2y)) = x*(A*x^2+B), B = -2*log2e*0.79788456, A = B*0.044715
    float s = l + r;
    float x = fmaf(s * rstd, g, be);
    float x2 = x * x;
    float q = x * fmaf(-0.10294340f, x2, -2.30220935f);
    float eq = __builtin_amdgcn_exp2f(q);
    float ge = x * __builtin_amdgcn_rcpf(1.f + eq);
    acc = fmaf(ge, w, acc);
}

__global__ __launch_bounds__(256) void k_pair(const float* __restrict__ W,
                                              const float* __restrict__ var,
                                              const float* __restrict__ gf,
                                              const float* __restrict__ bef,
                                              const float* __restrict__ wf,
                                              const float* __restrict__ b2f,
                                              float* __restrict__ out) {
    __shared__ float ls[16][260];   // 260 mod 32 = 4
    __shared__ float rs[16][260];
    __shared__ float red[4096];     // [ks][pt][c] partials, 16KB
    __shared__ float rstd_s[256];

    // decode upper-triangle tile index b -> (I, J), I<=J, 32 tile-rows
    const int b = blockIdx.x;
    int I = (int)((65.0f - sqrtf(4225.0f - 8.0f * (float)b)) * 0.5f);
    if (I < 0) I = 0;
    if (I > 31) I = 31;
#define S_(i) (32 * (i) - ((i) * ((i)-1)) / 2)
    while (S_(I) > b) --I;
    while (S_(I + 1) <= b) ++I;
    const int J = I + (b - S_(I));
#undef S_

    const int t = threadIdx.x;
    const int ks = t & 15, pt = t >> 4;
    const int i4 = (pt & 3) * 4, j4 = (pt >> 2) * 4;
    const int Ibase = I * 16, Jbase = N_ + J * 16;

    // ---- pass A: cov (4x4 block, 16 chains) ----
    float cv[16];
#pragma unroll
    for (int c = 0; c < 16; ++c) cv[c] = 0.f;
    for (int kb = 0; kb < D_; kb += 256) {
        for (int x = t; x < 16 * 64; x += 256) {
            int r = x >> 6, c4 = (x & 63) << 2;
            *(float4*)&ls[r][c4] = *(const float4*)&W[(Ibase + r) * D_ + kb + c4];
            *(float4*)&rs[r][c4] = *(const float4*)&W[(Jbase + r) * D_ + kb + c4];
        }
        __syncthreads();
#pragma unroll
        for (int it = 0; it < 4; ++it) {
            const int kq = (it * 16 + ks) * 4;
            float4 lq[4], rq[4];
#pragma unroll
            for (int d = 0; d < 4; ++d) {
                lq[d] = *(float4*)&ls[i4 + d][kq];
                rq[d] = *(float4*)&rs[j4 + d][kq];
            }
#pragma unroll
            for (int di = 0; di < 4; ++di)
#pragma unroll
                for (int dj = 0; dj < 4; ++dj)
                    cv[di * 4 + dj] += lq[di].x * rq[dj].x + lq[di].y * rq[dj].y +
                                       lq[di].z * rq[dj].z + lq[di].w * rq[dj].w;
        }
        __syncthreads();
    }
#pragma unroll
    for (int c = 0; c < 16; ++c) red[ks * 256 + pt * 16 + c] = cv[c];
    __syncthreads();

    // reduce + rstd: thread t -> pair (ri = t>>4, rj = t&15)
    const int ri = t >> 4, rj = t & 15;
    const int rpt = (ri >> 2) + ((rj >> 2) << 2);
    const int rc = (ri & 3) * 4 + (rj & 3);
    {
        float cov = 0.f;
#pragma unroll
        for (int k2 = 0; k2 < 16; ++k2) cov += red[k2 * 256 + rpt * 16 + rc];
        float varh = var[Ibase + ri] + var[Jbase + rj] + cov * (2.f / D_) + 1e-5f;
        rstd_s[t] = rsqrtf(varh);
    }
    __syncthreads();

    // ---- pass B: gelu dot (16 chains) ----
    float rst[16];
#pragma unroll
    for (int di = 0; di < 4; ++di)
#pragma unroll
        for (int dj = 0; dj < 4; ++dj)
            rst[di * 4 + dj] = rstd_s[(i4 + di) * 16 + (j4 + dj)];
    float ac[16];
#pragma unroll
    for (int c = 0; c < 16; ++c) ac[c] = 0.f;
    for (int kb = 0; kb < D_; kb += 256) {
        for (int x = t; x < 16 * 64; x += 256) {
            int r = x >> 6, c4 = (x & 63) << 2;
            *(float4*)&ls[r][c4] = *(const float4*)&W[(Ibase + r) * D_ + kb + c4];
            *(float4*)&rs[r][c4] = *(const float4*)&W[(Jbase + r) * D_ + kb + c4];
        }
        __syncthreads();
#pragma unroll
        for (int it = 0; it < 4; ++it) {
            const int kq = (it * 16 + ks) * 4;
            float4 g4 = *(const float4*)&gf[kb + kq];
            float4 be4 = *(const float4*)&bef[kb + kq];
            float4 w4 = *(const float4*)&wf[kb + kq];
            float4 lq[4], rq[4];
#pragma unroll
            for (int d = 0; d < 4; ++d) {
                lq[d] = *(float4*)&ls[i4 + d][kq];
                rq[d] = *(float4*)&rs[j4 + d][kq];
            }
#pragma unroll
            for (int di = 0; di < 4; ++di)
#pragma unroll
                for (int dj = 0; dj < 4; ++dj) {
                    float rr = rst[di * 4 + dj];
                    float& a = ac[di * 4 + dj];
                    gelu_acc(lq[di].x, rq[dj].x, g4.x, be4.x, w4.x, rr, a);
                    gelu_acc(lq[di].y, rq[dj].y, g4.y, be4.y, w4.y, rr, a);
                    gelu_acc(lq[di].z, rq[dj].z, g4.z, be4.z, w4.z, rr, a);
                    gelu_acc(lq[di].w, rq[dj].w, g4.w, be4.w, w4.w, rr, a);
                }
        }
        __syncthreads();
    }
#pragma unroll
    for (int c = 0; c < 16; ++c) red[ks * 256 + pt * 16 + c] = ac[c];
    __syncthreads();

    // final: thread t -> pair (ri, rj); coalesced primary store (rj fast)
    {
        float z = b2f[0];
#pragma unroll
        for (int k2 = 0; k2 < 16; ++k2) z += red[k2 * 256 + rpt * 16 + rc];
        float sg = __builtin_amdgcn_rcpf(1.f + __builtin_amdgcn_exp2f(-1.44269504f * z));
        const int gi = Ibase + ri, gj = (Jbase - N_) + rj;
        if (gi <= gj) {
            out[gi * N_ + gj] = sg;
            out[gj * N_ + gi] = sg;
        }
    }
}

extern "C" void kernel_launch(void* const* d_in, const int* in_sizes, int n_in,
                              void* d_out, int out_size, void* d_ws, size_t ws_size,
                              hipStream_t stream) {
    const float* E     = (const float*)d_in[0];
    const float* W1    = (const float*)d_in[1];
    const float* b1    = (const float*)d_in[2];
    const float* gamma = (const float*)d_in[3];
    const float* beta  = (const float*)d_in[4];
    const float* w2    = (const float*)d_in[5];
    const float* b2    = (const float*)d_in[6];
    float* out = (float*)d_out;

    float* F    = (float*)d_ws;
    float* lcrc = F;                  // [1024][512]: rows 0..511 lc, 512..1023 rc(+b1)
    float* var  = F + 1024 * 512;     // [1024]

    k_gemm<<<256, 256, 0, stream>>>(E, W1, b1, lcrc);
    k_center<<<1024, 256, 0, stream>>>(lcrc, var);
    k_pair<<<528, 256, 0, stream>>>(lcrc, var, gamma, beta, w2, b2, out);
}